// Round 11
// baseline (138.804 us; speedup 1.0000x reference)
//
#include <hip/hip_runtime.h>

// CREStereo grouped correlation, round 23.
// R22 post-mortem: asm counted-vmcnt pipeline = -1.3us corr (42.1), total
// 134.4 best; but VGPR gate failed (64, not 130+) and occupancy 34%
// (512-thr blocks cap 4/CU). R18's 256-thr structure measured 58% occ.
// R23 composes the only two +ve levers ever measured on corr:
//   (a) R22 asm counted-vmcnt 3-batch tap pipeline (verbatim)
//   (b) 256-thr / 8-px blocks for occupancy headroom (4608 blocks, 8/CU)
// plus the leanest barrier structure: meta from GLOBAL flow/extra (R17
// style, overlaps left staging), ONE barrier, direct masked stores.
// Predict occ -> 50-60%, corr 42 -> 36-39, total -> 128-131.
// PRE-COMMIT: corr <2us move => structural floor, declare next round.

namespace {
constexpr int kB = 2;
constexpr int kC = 256;
constexpr int kH = 96;
constexpr int kW = 192;
constexpr int kG = 4;
constexpr int kGC = kC / kG;              // 64
constexpr int kK = 9;
constexpr int kHW = kH * kW;              // 18432
constexpr size_t kPlane = (size_t)kC * kHW;
constexpr int kTransBlocks = (kHW / 64) * (kC / 64) * kB;       // 2304 (right only)
constexpr int kPx = 8;                                          // px per corr block
constexpr int kCorrBlocks  = kB * kHW / kPx;                    // 4608
}

typedef _Float16 half8_t __attribute__((ext_vector_type(8)));
typedef _Float16 half2_t __attribute__((ext_vector_type(2)));

struct TapMeta {        // 32 B: one (b,px,k) candidate
  int4   off;           // element offsets of 4 taps into right_t plane
  float4 wgt;           // bilinear weights (validity folded in)
};

__device__ __forceinline__ float dot8(half8_t a, half8_t b, float acc) {
#if __has_builtin(__builtin_amdgcn_fdot2)
  #pragma unroll
  for (int i = 0; i < 4; ++i) {
    half2_t a2 = {a[2 * i], a[2 * i + 1]};
    half2_t b2 = {b[2 * i], b[2 * i + 1]};
    acc = __builtin_amdgcn_fdot2(a2, b2, acc, false);
  }
#else
  #pragma unroll
  for (int i = 0; i < 8; ++i) acc += (float)a[i] * (float)b[i];
#endif
  return acc;
}

// raw 16B load: completion managed by manual counted s_waitcnt.
__device__ __forceinline__ half8_t ld16(const _Float16* p) {
  half8_t r;
  asm volatile("global_load_dwordx4 %0, %1, off"
               : "=&v"(r) : "v"(p));
  return r;
}

// ---- pre-pass: fp32->fp16 64x64 transpose of RIGHT only, 2304 blocks ----
__global__ __launch_bounds__(256) void prepass_kernel(
    const float* __restrict__ right, _Float16* __restrict__ right_t)
{
  __shared__ float tile[64][65];
  int tb = blockIdx.x;
  int pt = tb % (kHW / 64);         // pixel tile 0..287
  int ct = (tb / (kHW / 64)) % 4;   // channel tile 0..3
  int b  = tb / ((kHW / 64) * 4);   // batch
  int p0 = pt * 64, c0 = ct * 64;
  const float* inb = right + (size_t)b * kPlane;
  _Float16*   outb = right_t + (size_t)b * kPlane;
  int t = threadIdx.x;
  int cl = t >> 2;
  int q  = t & 3;
  #pragma unroll
  for (int i = 0; i < 4; ++i) {
    int j = q + 4 * i;
    float4 v = *(const float4*)(inb + (size_t)(c0 + cl) * kHW + p0 + 4 * j);
    tile[cl][4 * j + 0] = v.x;
    tile[cl][4 * j + 1] = v.y;
    tile[cl][4 * j + 2] = v.z;
    tile[cl][4 * j + 3] = v.w;
  }
  __syncthreads();
  int pl8 = t >> 3;                 // pixel 0..31 (+32*i)
  int c8  = t & 7;                  // channel octet
  #pragma unroll
  for (int i = 0; i < 2; ++i) {
    int px = pl8 + 32 * i;
    half8_t hv;
    #pragma unroll
    for (int j = 0; j < 8; ++j)
      hv[j] = (_Float16)tile[8 * c8 + j][px];
    *(half8_t*)(outb + (size_t)(p0 + px) * kC + c0 + 8 * c8) = hv;
  }
}

// ---- main: block = 8 px, 256 thr (4 waves); wave = 2 px x 32 lanes ----
// R23: 1-barrier prologue + asm counted-vmcnt pipeline + direct stores.
__global__ __launch_bounds__(256, 4) void corr_fp16_kernel(
    const _Float16* __restrict__ right_t, const float* __restrict__ left,
    const float* __restrict__ flow, const float* __restrict__ extra,
    float* __restrict__ out)
{
  __shared__ TapMeta  smeta[kPx * kK];      // 2304 B
  __shared__ _Float16 smleft[kPx][kC];      // 4 KB

  // XCD-chunked swizzle: 4608 blocks -> XCD i owns blocks [i*576,(i+1)*576).
  int sb = (blockIdx.x & 7) * (kCorrBlocks / 8) + (blockIdx.x >> 3);
  int blockPix = sb * kPx;              // first of 8 pixels (global, b-major)
  int b    = blockPix / kHW;            // blocks never straddle batch
  int pix0 = blockPix % kHW;            // 8-aligned; 8|W -> same image row

  int t = threadIdx.x;

  // (1) left gather, semi-coalesced: 2 lanes per 32B px-row chunk.
  //     c = t>>1 (+128*it), q = t&1 selects px half: float4 = 4 px.
  #pragma unroll
  for (int it = 0; it < 2; ++it) {
    int c = (t >> 1) + 128 * it;
    int q = t & 1;
    float4 v = *(const float4*)(left + (size_t)b * kPlane +
                                (size_t)c * kHW + pix0 + 4 * q);
    smleft[4 * q + 0][c] = (_Float16)v.x;
    smleft[4 * q + 1][c] = (_Float16)v.y;
    smleft[4 * q + 2][c] = (_Float16)v.z;
    smleft[4 * q + 3][c] = (_Float16)v.w;
  }

  // (2) meta from GLOBAL flow/extra (overlaps (1)): t<72 -> (px=t/9, k=t%9).
  if (t < kPx * kK) {
    int px = t / kK;
    int k  = t - px * kK;
    int gpix = pix0 + px;
    int w = gpix % kW, h = gpix / kW;

    const float* flowb = flow + (size_t)b * 2 * kHW + gpix;
    float bx = (float)w + flowb[0];
    float by = (float)h + flowb[kHW];
    const float* extb = extra + (size_t)b * 2 * kK * kHW + gpix;

    float xx = bx + (float)(k - 4) + extb[(size_t)(2 * k) * kHW];
    float yy = by + extb[(size_t)(2 * k + 1) * kHW];
    float xf = floorf(xx), yf = floorf(yy);
    float fx = xx - xf, fy = yy - yf;
    int ix0 = (int)xf, iy0 = (int)yf;
    int ix1 = ix0 + 1, iy1 = iy0 + 1;
    bool vx0 = (ix0 >= 0) && (ix0 < kW);
    bool vx1 = (ix1 >= 0) && (ix1 < kW);
    bool vy0 = (iy0 >= 0) && (iy0 < kH);
    bool vy1 = (iy1 >= 0) && (iy1 < kH);
    int xc0 = min(max(ix0, 0), kW - 1);
    int xc1 = min(max(ix1, 0), kW - 1);
    int yc0 = min(max(iy0, 0), kH - 1);
    int yc1 = min(max(iy1, 0), kH - 1);
    float wx0 = 1.f - fx, wy0 = 1.f - fy;
    TapMeta m;
    m.off.x = (yc0 * kW + xc0) * kC;
    m.off.y = (yc0 * kW + xc1) * kC;
    m.off.z = (yc1 * kW + xc0) * kC;
    m.off.w = (yc1 * kW + xc1) * kC;
    m.wgt.x = wx0 * wy0 * ((vx0 && vy0) ? 1.f : 0.f);
    m.wgt.y = fx  * wy0 * ((vx1 && vy0) ? 1.f : 0.f);
    m.wgt.z = wx0 * fy  * ((vx0 && vy1) ? 1.f : 0.f);
    m.wgt.w = fx  * fy  * ((vx1 && vy1) ? 1.f : 0.f);
    smeta[t] = m;
  }

  int wv   = t >> 6;                    // wave in block 0..3
  int lane = t & 63;
  int p    = lane >> 5;                 // pixel cluster 0..1
  int cl   = lane & 31;                 // channel-lane: owns channels cl*8..cl*8+7
  int px   = wv * 2 + p;                // block-local pixel 0..7
  int pix  = pix0 + px;

  const _Float16* Rb = right_t + (size_t)b * kPlane + cl * 8;

  __syncthreads();                      // ONE barrier: smeta + smleft ready

  half8_t l8 = *(const half8_t*)&smleft[px][cl * 8];
  const TapMeta* mp = smeta + px * kK;  // LDS, broadcast reads

  float rr[kK];
  half8_t tA[12], tB[12], tC[12];

#define ISSUE_TAPS(T, KB) do {                                           \
    int4 o0 = mp[(KB)].off, o1 = mp[(KB) + 1].off, o2 = mp[(KB) + 2].off; \
    T[0]  = ld16(Rb + o0.x);                                             \
    T[1]  = ld16(Rb + o0.y);                                             \
    T[2]  = ld16(Rb + o0.z);                                             \
    T[3]  = ld16(Rb + o0.w);                                             \
    T[4]  = ld16(Rb + o1.x);                                             \
    T[5]  = ld16(Rb + o1.y);                                             \
    T[6]  = ld16(Rb + o1.z);                                             \
    T[7]  = ld16(Rb + o1.w);                                             \
    T[8]  = ld16(Rb + o2.x);                                             \
    T[9]  = ld16(Rb + o2.y);                                             \
    T[10] = ld16(Rb + o2.z);                                             \
    T[11] = ld16(Rb + o2.w);                                             \
  } while (0)

#define COMP_TAPS(T, KB) do {                                      \
    _Pragma("unroll")                                              \
    for (int j = 0; j < 3; ++j) {                                  \
      float4 w4 = mp[(KB) + j].wgt;                                \
      float d00 = dot8(T[4 * j + 0], l8, 0.f);                     \
      float d01 = dot8(T[4 * j + 1], l8, 0.f);                     \
      float d10 = dot8(T[4 * j + 2], l8, 0.f);                     \
      float d11 = dot8(T[4 * j + 3], l8, 0.f);                     \
      float r = w4.x * d00 + w4.y * d01 + w4.z * d10 + w4.w * d11; \
      r += __shfl_xor(r, 1);                                       \
      r += __shfl_xor(r, 2);                                       \
      r += __shfl_xor(r, 4);                                       \
      rr[(KB) + j] = r;                                            \
    }                                                              \
  } while (0)

  // counted-vmcnt 3-batch pipeline (24 loads in flight at peak)
  ISSUE_TAPS(tA, 0);                              // vmcnt: 12
  ISSUE_TAPS(tB, 3);                              // vmcnt: 24
  asm volatile("s_waitcnt vmcnt(12)" ::: "memory");   // A complete
  __builtin_amdgcn_sched_barrier(0);
  COMP_TAPS(tA, 0);
  ISSUE_TAPS(tC, 6);                              // vmcnt: 24
  asm volatile("s_waitcnt vmcnt(12)" ::: "memory");   // B complete
  __builtin_amdgcn_sched_barrier(0);
  COMP_TAPS(tB, 3);
  asm volatile("s_waitcnt vmcnt(0)" ::: "memory");    // C complete
  __builtin_amdgcn_sched_barrier(0);
  COMP_TAPS(tC, 6);

#undef ISSUE_TAPS
#undef COMP_TAPS

  // direct masked store block: exec mask changes once
  int g = cl >> 3;
  if ((cl & 7) == 0) {
    float* outp = out + ((size_t)b * kG + g) * kK * kHW + pix;
    #pragma unroll
    for (int k = 0; k < kK; ++k)
      outp[(size_t)k * kHW] = rr[k] * (1.f / kGC);
  }
}

// ---- fallback (round-2 kernel) if workspace too small ----
__global__ __launch_bounds__(256) void crestereo_corr_fallback(
    const float* __restrict__ left, const float* __restrict__ right,
    const float* __restrict__ flow, const float* __restrict__ extra,
    float* __restrict__ out)
{
  int t = blockIdx.x * blockDim.x + threadIdx.x;
  int w = t % kW;
  int h = (t / kW) % kH;
  int k = (t / kHW) % kK;
  int g = (t / (kHW * kK)) % kG;
  int b = t / (kHW * kK * kG);

  int pix = h * kW + w;
  const float* flowb = flow + b * 2 * kHW + pix;
  float x = (float)(w + (k - 4)) + flowb[0];
  float y = (float)h + flowb[kHW];
  const float* extb = extra + (size_t)(b * 2 * kK + 2 * k) * kHW + pix;
  x += extb[0];
  y += extb[kHW];

  float xf = floorf(x), yf = floorf(y);
  float fx = x - xf, fy = y - yf;
  int ix0 = (int)xf, iy0 = (int)yf;
  int ix1 = ix0 + 1, iy1 = iy0 + 1;
  bool vx0 = (ix0 >= 0) && (ix0 < kW);
  bool vx1 = (ix1 >= 0) && (ix1 < kW);
  bool vy0 = (iy0 >= 0) && (iy0 < kH);
  bool vy1 = (iy1 >= 0) && (iy1 < kH);
  int xc0 = min(max(ix0, 0), kW - 1);
  int xc1 = min(max(ix1, 0), kW - 1);
  int yc0 = min(max(iy0, 0), kH - 1);
  int yc1 = min(max(iy1, 0), kH - 1);
  float wx0 = 1.f - fx, wy0 = 1.f - fy;
  float w00 = wx0 * wy0 * ((vx0 && vy0) ? 1.f : 0.f);
  float w01 = fx  * wy0 * ((vx1 && vy0) ? 1.f : 0.f);
  float w10 = wx0 * fy  * ((vx0 && vy1) ? 1.f : 0.f);
  float w11 = fx  * fy  * ((vx1 && vy1) ? 1.f : 0.f);
  int idx = yc0 * kW + xc0;
  int dx  = xc1 - xc0;
  int dyw = (yc1 - yc0) * kW;

  const float* Rb = right + (size_t)(b * kC + g * kGC) * kHW + idx;
  const float* Lb = left  + (size_t)(b * kC + g * kGC) * kHW + pix;

  float acc = 0.f;
  #pragma unroll 4
  for (int c = 0; c < kGC; ++c) {
    const float* Rc = Rb + (size_t)c * kHW;
    float l   = Lb[(size_t)c * kHW];
    acc += l * (w00 * Rc[0] + w01 * Rc[dx] + w10 * Rc[dyw] + w11 * Rc[dx + dyw]);
  }
  out[(size_t)((b * kG + g) * kK + k) * kHW + pix] = acc * (1.f / kGC);
}

extern "C" void kernel_launch(void* const* d_in, const int* in_sizes, int n_in,
                              void* d_out, int out_size, void* d_ws, size_t ws_size,
                              hipStream_t stream) {
  const float* left  = (const float*)d_in[0];
  const float* right = (const float*)d_in[1];
  const float* flow  = (const float*)d_in[2];
  const float* extra = (const float*)d_in[3];
  float* out = (float*)d_out;

  size_t t_bytes = (size_t)kB * kPlane * sizeof(_Float16);   // 18.9 MB (right_t)
  if (ws_size >= t_bytes) {
    _Float16* right_t = (_Float16*)d_ws;

    prepass_kernel<<<kTransBlocks, 256, 0, stream>>>(right, right_t);
    corr_fp16_kernel<<<kCorrBlocks, 256, 0, stream>>>(
        right_t, left, flow, extra, out);
  } else {
    int total = kB * kG * kK * kH * kW;
    crestereo_corr_fallback<<<(total + 255) / 256, 256, 0, stream>>>(
        left, right, flow, extra, out);
  }
}

// Round 12
// 134.671 us; speedup vs baseline: 1.0307x; 1.0307x over previous
//
#include <hip/hip_runtime.h>

// CREStereo grouped correlation, round 24 (= R22 restored verbatim).
// R23 post-mortem: occupancy x depth composition FAILED (occ stayed 33%,
// corr regressed 42.1 -> 44.3, total 138.8). Pre-commitment triggered:
// corr is at a structural latency floor -- tap gather = 36 coalesced-512B
// loads/wave, byte floor ~9-10us, line floor ~19-25us, measured ~42us with
// the gap = ~3 exposed L2 waits x ~500cy at ~2.7 resident waves/SIMD.
// All depth mechanisms (compiler sched, launch bounds, sched_barrier,
// asm counted-vmcnt) and all byte/line reductions tried; only the asm
// pipeline reproduced (-1.3us). Restoring best verified state (R22,
// 134.4us). Expect total ~134-135; then declare roofline.

namespace {
constexpr int kB = 2;
constexpr int kC = 256;
constexpr int kH = 96;
constexpr int kW = 192;
constexpr int kG = 4;
constexpr int kGC = kC / kG;              // 64
constexpr int kK = 9;
constexpr int kHW = kH * kW;              // 18432
constexpr size_t kPlane = (size_t)kC * kHW;
constexpr int kTransBlocks = (kHW / 64) * (kC / 64) * kB;       // 2304 (right only)
constexpr int kPx = 16;                                         // px per corr block
constexpr int kCorrBlocks  = kB * kHW / kPx;                    // 2304
}

typedef _Float16 half8_t __attribute__((ext_vector_type(8)));
typedef _Float16 half2_t __attribute__((ext_vector_type(2)));

struct TapMeta {        // 32 B: one (b,px,k) candidate
  int4   off;           // element offsets of 4 taps into right_t plane
  float4 wgt;           // bilinear weights (validity folded in)
};

__device__ __forceinline__ float dot8(half8_t a, half8_t b, float acc) {
#if __has_builtin(__builtin_amdgcn_fdot2)
  #pragma unroll
  for (int i = 0; i < 4; ++i) {
    half2_t a2 = {a[2 * i], a[2 * i + 1]};
    half2_t b2 = {b[2 * i], b[2 * i + 1]};
    acc = __builtin_amdgcn_fdot2(a2, b2, acc, false);
  }
#else
  #pragma unroll
  for (int i = 0; i < 8; ++i) acc += (float)a[i] * (float)b[i];
#endif
  return acc;
}

// raw 16B load -- compiler can't serialize/reschedule these; completion
// is managed by manual counted s_waitcnt below.
__device__ __forceinline__ half8_t ld16(const _Float16* p) {
  half8_t r;
  asm volatile("global_load_dwordx4 %0, %1, off"
               : "=&v"(r) : "v"(p));
  return r;
}

// ---- pre-pass: fp32->fp16 64x64 transpose of RIGHT only, 2304 blocks ----
__global__ __launch_bounds__(256) void prepass_kernel(
    const float* __restrict__ right, _Float16* __restrict__ right_t)
{
  __shared__ float tile[64][65];
  int tb = blockIdx.x;
  int pt = tb % (kHW / 64);         // pixel tile 0..287
  int ct = (tb / (kHW / 64)) % 4;   // channel tile 0..3
  int b  = tb / ((kHW / 64) * 4);   // batch
  int p0 = pt * 64, c0 = ct * 64;
  const float* inb = right + (size_t)b * kPlane;
  _Float16*   outb = right_t + (size_t)b * kPlane;
  int t = threadIdx.x;
  int cl = t >> 2;
  int q  = t & 3;
  #pragma unroll
  for (int i = 0; i < 4; ++i) {
    int j = q + 4 * i;
    float4 v = *(const float4*)(inb + (size_t)(c0 + cl) * kHW + p0 + 4 * j);
    tile[cl][4 * j + 0] = v.x;
    tile[cl][4 * j + 1] = v.y;
    tile[cl][4 * j + 2] = v.z;
    tile[cl][4 * j + 3] = v.w;
  }
  __syncthreads();
  int pl8 = t >> 3;                 // pixel 0..31 (+32*i)
  int c8  = t & 7;                  // channel octet
  #pragma unroll
  for (int i = 0; i < 2; ++i) {
    int px = pl8 + 32 * i;
    half8_t hv;
    #pragma unroll
    for (int j = 0; j < 8; ++j)
      hv[j] = (_Float16)tile[8 * c8 + j][px];
    *(half8_t*)(outb + (size_t)(p0 + px) * kC + c0 + 8 * c8) = hv;
  }
}

// ---- main: block = 16 px, 512 thr (8 waves); wave = 2 px x 32 lanes ----
// asm counted-vmcnt 3-batch tap pipeline (R22 best-verified config).
__global__ __launch_bounds__(512, 2) void corr_fp16_kernel(
    const _Float16* __restrict__ right_t, const float* __restrict__ left,
    const float* __restrict__ flow, const float* __restrict__ extra,
    float* __restrict__ out)
{
  __shared__ _Float16 smleft[kPx][kC];      // 8 KB
  __shared__ float    smflow[20][kPx];      // 1280 B: rows 0-1 flow, 2-19 extra
  __shared__ TapMeta  smeta[kPx * kK];      // 4608 B
  __shared__ float    smout[kG * kK][kPx];  // 2304 B

  // XCD-chunked swizzle: 2304 blocks -> XCD i owns blocks [i*288,(i+1)*288).
  int sb = (blockIdx.x & 7) * (kCorrBlocks / 8) + (blockIdx.x >> 3);
  int blockPix = sb * kPx;              // first of 16 pixels (global, b-major)
  int b    = blockPix / kHW;            // blocks never straddle batch
  int pix0 = blockPix % kHW;            // 16-aligned; 16|W -> same image row

  int t = threadIdx.x;

  // (1) left gather, coalesced: 4 consecutive lanes cover one 64B ch-row.
  #pragma unroll
  for (int it = 0; it < 2; ++it) {
    int c = (t >> 2) + 128 * it;
    int q = t & 3;
    float4 v = *(const float4*)(left + (size_t)b * kPlane +
                                (size_t)c * kHW + pix0 + 4 * q);
    smleft[4 * q + 0][c] = (_Float16)v.x;
    smleft[4 * q + 1][c] = (_Float16)v.y;
    smleft[4 * q + 2][c] = (_Float16)v.z;
    smleft[4 * q + 3][c] = (_Float16)v.w;
  }

  // (2) flow/extra stage: t<320 loads one float; each row = one 64B line.
  if (t < 320) {
    int fr = t >> 4, fpx = t & 15;
    const float* src = (fr < 2)
        ? flow  + ((size_t)b * 2  + fr)       * kHW + pix0 + fpx
        : extra + ((size_t)b * 18 + (fr - 2)) * kHW + pix0 + fpx;
    smflow[fr][fpx] = *src;
  }
  __syncthreads();

  // (3) meta math from LDS: t<144 computes TapMeta for (px=t/9, k=t%9).
  if (t < kPx * kK) {
    int px = t / kK;
    int k  = t - px * kK;
    int gpix = pix0 + px;
    int w = gpix % kW, h = gpix / kW;

    float bx = (float)w + smflow[0][px];
    float by = (float)h + smflow[1][px];
    float xx = bx + (float)(k - 4) + smflow[2 + 2 * k][px];
    float yy = by + smflow[2 + 2 * k + 1][px];
    float xf = floorf(xx), yf = floorf(yy);
    float fx = xx - xf, fy = yy - yf;
    int ix0 = (int)xf, iy0 = (int)yf;
    int ix1 = ix0 + 1, iy1 = iy0 + 1;
    bool vx0 = (ix0 >= 0) && (ix0 < kW);
    bool vx1 = (ix1 >= 0) && (ix1 < kW);
    bool vy0 = (iy0 >= 0) && (iy0 < kH);
    bool vy1 = (iy1 >= 0) && (iy1 < kH);
    int xc0 = min(max(ix0, 0), kW - 1);
    int xc1 = min(max(ix1, 0), kW - 1);
    int yc0 = min(max(iy0, 0), kH - 1);
    int yc1 = min(max(iy1, 0), kH - 1);
    float wx0 = 1.f - fx, wy0 = 1.f - fy;
    TapMeta m;
    m.off.x = (yc0 * kW + xc0) * kC;
    m.off.y = (yc0 * kW + xc1) * kC;
    m.off.z = (yc1 * kW + xc0) * kC;
    m.off.w = (yc1 * kW + xc1) * kC;
    m.wgt.x = wx0 * wy0 * ((vx0 && vy0) ? 1.f : 0.f);
    m.wgt.y = fx  * wy0 * ((vx1 && vy0) ? 1.f : 0.f);
    m.wgt.z = wx0 * fy  * ((vx0 && vy1) ? 1.f : 0.f);
    m.wgt.w = fx  * fy  * ((vx1 && vy1) ? 1.f : 0.f);
    smeta[t] = m;
  }

  int wv   = t >> 6;                    // wave in block 0..7
  int lane = t & 63;
  int p    = lane >> 5;                 // pixel cluster 0..1
  int cl   = lane & 31;                 // channel-lane: owns channels cl*8..cl*8+7
  int px   = wv * 2 + p;                // block-local pixel 0..15

  const _Float16* Rb = right_t + (size_t)b * kPlane + cl * 8;

  __syncthreads();                      // drains vmcnt/lgkmcnt -> clean slate

  half8_t l8 = *(const half8_t*)&smleft[px][cl * 8];
  const TapMeta* mp = smeta + px * kK;  // LDS, broadcast reads

  float rr[kK];
  half8_t tA[12], tB[12], tC[12];

#define ISSUE_TAPS(T, KB) do {                                           \
    int4 o0 = mp[(KB)].off, o1 = mp[(KB) + 1].off, o2 = mp[(KB) + 2].off; \
    T[0]  = ld16(Rb + o0.x);                                             \
    T[1]  = ld16(Rb + o0.y);                                             \
    T[2]  = ld16(Rb + o0.z);                                             \
    T[3]  = ld16(Rb + o0.w);                                             \
    T[4]  = ld16(Rb + o1.x);                                             \
    T[5]  = ld16(Rb + o1.y);                                             \
    T[6]  = ld16(Rb + o1.z);                                             \
    T[7]  = ld16(Rb + o1.w);                                             \
    T[8]  = ld16(Rb + o2.x);                                             \
    T[9]  = ld16(Rb + o2.y);                                             \
    T[10] = ld16(Rb + o2.z);                                             \
    T[11] = ld16(Rb + o2.w);                                             \
  } while (0)

#define COMP_TAPS(T, KB) do {                                      \
    _Pragma("unroll")                                              \
    for (int j = 0; j < 3; ++j) {                                  \
      float4 w4 = mp[(KB) + j].wgt;                                \
      float d00 = dot8(T[4 * j + 0], l8, 0.f);                     \
      float d01 = dot8(T[4 * j + 1], l8, 0.f);                     \
      float d10 = dot8(T[4 * j + 2], l8, 0.f);                     \
      float d11 = dot8(T[4 * j + 3], l8, 0.f);                     \
      float r = w4.x * d00 + w4.y * d01 + w4.z * d10 + w4.w * d11; \
      r += __shfl_xor(r, 1);                                       \
      r += __shfl_xor(r, 2);                                       \
      r += __shfl_xor(r, 4);                                       \
      rr[(KB) + j] = r;                                            \
    }                                                              \
  } while (0)

  // counted-vmcnt 3-batch pipeline (24 loads in flight at peak)
  ISSUE_TAPS(tA, 0);                              // vmcnt: 12
  ISSUE_TAPS(tB, 3);                              // vmcnt: 24
  asm volatile("s_waitcnt vmcnt(12)" ::: "memory");   // A complete
  __builtin_amdgcn_sched_barrier(0);
  COMP_TAPS(tA, 0);
  ISSUE_TAPS(tC, 6);                              // vmcnt: 24
  asm volatile("s_waitcnt vmcnt(12)" ::: "memory");   // B complete
  __builtin_amdgcn_sched_barrier(0);
  COMP_TAPS(tB, 3);
  asm volatile("s_waitcnt vmcnt(0)" ::: "memory");    // C complete
  __builtin_amdgcn_sched_barrier(0);
  COMP_TAPS(tC, 6);

#undef ISSUE_TAPS
#undef COMP_TAPS

  // (4) epilogue: bounce rr through LDS, then coalesced 64B-row stores.
  if ((cl & 7) == 0) {
    int g = cl >> 3;
    #pragma unroll
    for (int k = 0; k < kK; ++k)
      smout[g * kK + k][px] = rr[k] * (1.f / kGC);
  }
  __syncthreads();
  {
    float* ob = out + (size_t)b * kG * kK * kHW + pix0;
    int r   = t >> 4;          // 0..31
    int px2 = t & 15;
    ob[(size_t)r * kHW + px2] = smout[r][px2];
    if (t < (kG * kK - 32) * kPx) {       // rows 32..35
      int r2 = 32 + (t >> 4);
      ob[(size_t)r2 * kHW + px2] = smout[r2][px2];
    }
  }
}

// ---- fallback (round-2 kernel) if workspace too small ----
__global__ __launch_bounds__(256) void crestereo_corr_fallback(
    const float* __restrict__ left, const float* __restrict__ right,
    const float* __restrict__ flow, const float* __restrict__ extra,
    float* __restrict__ out)
{
  int t = blockIdx.x * blockDim.x + threadIdx.x;
  int w = t % kW;
  int h = (t / kW) % kH;
  int k = (t / kHW) % kK;
  int g = (t / (kHW * kK)) % kG;
  int b = t / (kHW * kK * kG);

  int pix = h * kW + w;
  const float* flowb = flow + b * 2 * kHW + pix;
  float x = (float)(w + (k - 4)) + flowb[0];
  float y = (float)h + flowb[kHW];
  const float* extb = extra + (size_t)(b * 2 * kK + 2 * k) * kHW + pix;
  x += extb[0];
  y += extb[kHW];

  float xf = floorf(x), yf = floorf(y);
  float fx = x - xf, fy = y - yf;
  int ix0 = (int)xf, iy0 = (int)yf;
  int ix1 = ix0 + 1, iy1 = iy0 + 1;
  bool vx0 = (ix0 >= 0) && (ix0 < kW);
  bool vx1 = (ix1 >= 0) && (ix1 < kW);
  bool vy0 = (iy0 >= 0) && (iy0 < kH);
  bool vy1 = (iy1 >= 0) && (iy1 < kH);
  int xc0 = min(max(ix0, 0), kW - 1);
  int xc1 = min(max(ix1, 0), kW - 1);
  int yc0 = min(max(iy0, 0), kH - 1);
  int yc1 = min(max(iy1, 0), kH - 1);
  float wx0 = 1.f - fx, wy0 = 1.f - fy;
  float w00 = wx0 * wy0 * ((vx0 && vy0) ? 1.f : 0.f);
  float w01 = fx  * wy0 * ((vx1 && vy0) ? 1.f : 0.f);
  float w10 = wx0 * fy  * ((vx0 && vy1) ? 1.f : 0.f);
  float w11 = fx  * fy  * ((vx1 && vy1) ? 1.f : 0.f);
  int idx = yc0 * kW + xc0;
  int dx  = xc1 - xc0;
  int dyw = (yc1 - yc0) * kW;

  const float* Rb = right + (size_t)(b * kC + g * kGC) * kHW + idx;
  const float* Lb = left  + (size_t)(b * kC + g * kGC) * kHW + pix;

  float acc = 0.f;
  #pragma unroll 4
  for (int c = 0; c < kGC; ++c) {
    const float* Rc = Rb + (size_t)c * kHW;
    float l   = Lb[(size_t)c * kHW];
    acc += l * (w00 * Rc[0] + w01 * Rc[dx] + w10 * Rc[dyw] + w11 * Rc[dx + dyw]);
  }
  out[(size_t)((b * kG + g) * kK + k) * kHW + pix] = acc * (1.f / kGC);
}

extern "C" void kernel_launch(void* const* d_in, const int* in_sizes, int n_in,
                              void* d_out, int out_size, void* d_ws, size_t ws_size,
                              hipStream_t stream) {
  const float* left  = (const float*)d_in[0];
  const float* right = (const float*)d_in[1];
  const float* flow  = (const float*)d_in[2];
  const float* extra = (const float*)d_in[3];
  float* out = (float*)d_out;

  size_t t_bytes = (size_t)kB * kPlane * sizeof(_Float16);   // 18.9 MB (right_t)
  if (ws_size >= t_bytes) {
    _Float16* right_t = (_Float16*)d_ws;

    prepass_kernel<<<kTransBlocks, 256, 0, stream>>>(right, right_t);
    corr_fp16_kernel<<<kCorrBlocks, 512, 0, stream>>>(
        right_t, left, flow, extra, out);
  } else {
    int total = kB * kG * kK * kH * kW;
    crestereo_corr_fallback<<<(total + 255) / 256, 256, 0, stream>>>(
        left, right, flow, extra, out);
  }
}